// Round 3
// baseline (364.917 us; speedup 1.0000x reference)
//
#include <hip/hip_runtime.h>
#include <stdint.h>

// ---------------------------------------------------------------------------
// LocalAtomAttention on gfx950 — round 3: TRANSPOSED dataflow.
//   C^T = W @ x^T  (MFMA A = W rows = channels, B = x^T cols = atoms).
//   C-layout then puts ONE ATOM per lane (col = lane&15) with its channels in
//   registers; the 4 atoms of a residue live in one aligned 4-lane quad ->
//   all attention exchanges are DPP quad_perm (VALU), not LDS-pipe swizzles.
//   Only O round-trips LDS (16 KB, XOR-swizzled, b64 writes / b128 reads).
//   Out-proj also transposed: C2^T = Wo @ O^T. One barrier total.
// ---------------------------------------------------------------------------

typedef __bf16 bf16x8 __attribute__((ext_vector_type(8)));
typedef float  f32x4  __attribute__((ext_vector_type(4)));

#define N_RES 65536   // B*L
#define RPB   16      // residues per block
#define MROWS 64      // atom rows per block
#define CDIM  128

__device__ __forceinline__ uint32_t pk2(float a, float b) {
    uint32_t ua = __builtin_bit_cast(uint32_t, a) + 0x8000u;
    uint32_t ub = __builtin_bit_cast(uint32_t, b) + 0x8000u;
    return (ua >> 16) | (ub & 0xffff0000u);
}
__device__ __forceinline__ bf16x8 pack8(float4 f0, float4 f1) {
    uint4 uu = make_uint4(pk2(f0.x, f0.y), pk2(f0.z, f0.w),
                          pk2(f1.x, f1.y), pk2(f1.z, f1.w));
    return __builtin_bit_cast(bf16x8, uu);
}
// bit-permuted swizzle key of (row&15) — R2-measured zero read conflicts
__device__ __forceinline__ int swz_key(int row4) {
    return ((row4 & 2) << 2) | ((row4 & 8) >> 1) | ((row4 & 4) >> 1) | (row4 & 1);
}

// quad_perm DPP: value from lane (self ^ P) within each aligned 4-lane quad
#define QP_XOR1 0xB1   // [1,0,3,2]
#define QP_XOR2 0x4E   // [2,3,0,1]
#define QP_XOR3 0x1B   // [3,2,1,0]
template <int CTRL>
__device__ __forceinline__ int qpermi(int v) {
    return __builtin_amdgcn_update_dpp(0, v, CTRL, 0xF, 0xF, true);
}
template <int CTRL>
__device__ __forceinline__ float qpermf(float v) {
    return __builtin_bit_cast(float, qpermi<CTRL>(__builtin_bit_cast(int, v)));
}

// --------------------------- W fp32 -> bf16 pre-pass ------------------------
__global__ void wconv_kernel(const float* __restrict__ wq, const float* __restrict__ wk,
                             const float* __restrict__ wv, const float* __restrict__ wo,
                             uint16_t* __restrict__ dst) {
    int gid = blockIdx.x * 256 + threadIdx.x;   // 16384 threads x 4 elems
    int idx = gid * 4;
    int sel = idx >> 14;
    int off = idx & 16383;
    const float* s = (sel == 0) ? wq : (sel == 1) ? wk : (sel == 2) ? wv : wo;
    float4 f = *(const float4*)(s + off);
    uint2 u = make_uint2(pk2(f.x, f.y), pk2(f.z, f.w));
    *(uint2*)(dst + idx) = u;
}

// --------------------------------- main -------------------------------------
template <bool USEWS>
__global__ __launch_bounds__(256, 3)
void laa_main(const float* __restrict__ x, const int* __restrict__ mask,
              const float* __restrict__ Wq, const float* __restrict__ bq,
              const float* __restrict__ Wk, const float* __restrict__ bk,
              const float* __restrict__ Wv, const float* __restrict__ bv,
              const float* __restrict__ Wo, const float* __restrict__ bo,
              const uint16_t* __restrict__ wbf,
              float* __restrict__ out) {
    __shared__ uint16_t sO[MROWS * CDIM];   // 16 KB, XOR-swizzled

    const int tid  = threadIdx.x;
    const int w    = tid >> 6;        // wave == head; owns channels [w*32, w*32+32)
    const int lane = tid & 63;
    const int l    = lane & 15;       // atom column within a 16-atom tile
    const int q    = lane >> 4;       // channel quad / k-quad
    const long m0  = (long)blockIdx.x * MROWS;

    const f32x4 vzero = {0.f, 0.f, 0.f, 0.f};
    const float SC = 0.17677669529663689f;   // 1/sqrt(32)

    // per-lane bias float4s for this lane's 8 channels (mt=0,1; ch = w*32+mt*16+q*4+r)
    f32x4 bqv[2], bkv[2], bvv[2], bov[2];
    #pragma unroll
    for (int mt = 0; mt < 2; ++mt) {
        int ch = w * 32 + mt * 16 + q * 4;
        bqv[mt] = *(const f32x4*)(bq + ch);
        bkv[mt] = *(const f32x4*)(bk + ch);
        bvv[mt] = *(const f32x4*)(bv + ch);
        bov[mt] = *(const f32x4*)(bo + ch);
    }

    // ---- transposed Q/K/V GEMMs: acc[g][mt][n] = (W_g @ x^T) tile ----------
    f32x4 acc[3][2][4];
    #pragma unroll
    for (int g = 0; g < 3; ++g)
        #pragma unroll
        for (int mt = 0; mt < 2; ++mt)
            #pragma unroll
            for (int n = 0; n < 4; ++n) acc[g][mt][n] = vzero;

    const float* wsrc32[3] = {Wq, Wk, Wv};
    #pragma unroll
    for (int ks = 0; ks < 4; ++ks) {
        // B-frags: x^T  (lane = atom n*16+l, k = ks*32+q*8+j)
        bf16x8 xf[4];
        #pragma unroll
        for (int n = 0; n < 4; ++n) {
            const float4* p = (const float4*)(x + (m0 + n * 16 + l) * CDIM + ks * 32 + q * 8);
            xf[n] = pack8(p[0], p[1]);
        }
        // A-frags: W rows (m = ch = w*32+mt*16+l, k = ks*32+q*8+j)
        bf16x8 af[3][2];
        #pragma unroll
        for (int g = 0; g < 3; ++g) {
            #pragma unroll
            for (int mt = 0; mt < 2; ++mt) {
                int wrow = w * 32 + mt * 16 + l;
                if constexpr (USEWS) {
                    af[g][mt] = *(const bf16x8*)(wbf + g * 16384 + wrow * CDIM + ks * 32 + q * 8);
                } else {
                    const float* wp = wsrc32[g] + wrow * CDIM + ks * 32 + q * 8;
                    af[g][mt] = pack8(((const float4*)wp)[0], ((const float4*)wp)[1]);
                }
            }
        }
        #pragma unroll
        for (int g = 0; g < 3; ++g)
            #pragma unroll
            for (int mt = 0; mt < 2; ++mt)
                #pragma unroll
                for (int n = 0; n < 4; ++n)
                    acc[g][mt][n] = __builtin_amdgcn_mfma_f32_16x16x32_bf16(
                        af[g][mt], xf[n], acc[g][mt][n], 0, 0, 0);
    }

    // ---- attention: lane = atom (n*16+l); its residue's 3 partners are the
    //      aligned quad -> quad_perm exchanges; channel-sum via xor16/xor32 ---
    float rm[4];
    const int key = swz_key(l);
    #pragma unroll
    for (int n = 0; n < 4; ++n) {
        const int resg = blockIdx.x * RPB + n * 4 + (l >> 2);
        const int mk0 = mask[resg * 4 + (l & 3)];         // own atom's key-mask
        const int mk1 = qpermi<QP_XOR1>(mk0);
        const int mk2 = qpermi<QP_XOR2>(mk0);
        const int mk3 = qpermi<QP_XOR3>(mk0);
        rm[n] = (mk0 | mk1 | mk2 | mk3) ? 1.f : 0.f;

        float Qo[8], Ko[8], Vo[8];
        #pragma unroll
        for (int mt = 0; mt < 2; ++mt)
            #pragma unroll
            for (int r = 0; r < 4; ++r) {
                int c = mt * 4 + r;
                Qo[c] = acc[0][mt][n][r] + bqv[mt][r];
                Ko[c] = acc[1][mt][n][r] + bkv[mt][r];
                Vo[c] = acc[2][mt][n][r] + bvv[mt][r];
            }
        // partial scores t[ka = a ^ p] over this lane's 8 channels
        float t0 = 0.f, t1 = 0.f, t2 = 0.f, t3 = 0.f;
        #pragma unroll
        for (int c = 0; c < 8; ++c) {
            t0 += Qo[c] * Ko[c];
            t1 += Qo[c] * qpermf<QP_XOR1>(Ko[c]);
            t2 += Qo[c] * qpermf<QP_XOR2>(Ko[c]);
            t3 += Qo[c] * qpermf<QP_XOR3>(Ko[c]);
        }
        // reduce across the 4 channel-quads (lanes ^16, ^32)
        t0 += __shfl_xor(t0, 16); t0 += __shfl_xor(t0, 32);
        t1 += __shfl_xor(t1, 16); t1 += __shfl_xor(t1, 32);
        t2 += __shfl_xor(t2, 16); t2 += __shfl_xor(t2, 32);
        t3 += __shfl_xor(t3, 16); t3 += __shfl_xor(t3, 32);
        t0 *= SC; t1 *= SC; t2 *= SC; t3 *= SC;

        // masked softmax for OWN query row (qa = own atom)
        float mx = -3.0e38f;
        if (mk0) mx = fmaxf(mx, t0);
        if (mk1) mx = fmaxf(mx, t1);
        if (mk2) mx = fmaxf(mx, t2);
        if (mk3) mx = fmaxf(mx, t3);
        float e0 = mk0 ? __expf(t0 - mx) : 0.f;
        float e1 = mk1 ? __expf(t1 - mx) : 0.f;
        float e2 = mk2 ? __expf(t2 - mx) : 0.f;
        float e3 = mk3 ? __expf(t3 - mx) : 0.f;
        float ssum = e0 + e1 + e2 + e3;
        float inv = ssum > 0.f ? 1.f / ssum : 0.f;
        e0 *= inv; e1 *= inv; e2 *= inv; e3 *= inv;

        // PV: V[ka] via quad_perm; o = own atom's output row, 8 channels
        float o[8];
        #pragma unroll
        for (int c = 0; c < 8; ++c) {
            o[c] = e0 * Vo[c]
                 + e1 * qpermf<QP_XOR1>(Vo[c])
                 + e2 * qpermf<QP_XOR2>(Vo[c])
                 + e3 * qpermf<QP_XOR3>(Vo[c]);
        }
        // write O (bf16) to swizzled LDS: row = atom, 4-ch groups as b64
        const int row = n * 16 + l;
        #pragma unroll
        for (int mt = 0; mt < 2; ++mt) {
            uint2 d = make_uint2(pk2(o[mt * 4 + 0], o[mt * 4 + 1]),
                                 pk2(o[mt * 4 + 2], o[mt * 4 + 3]));
            const int c8 = w * 4 + mt * 2 + (q >> 1);
            *(uint2*)(sO + row * CDIM + ((c8 ^ key) << 3) + (q & 1) * 4) = d;
        }
    }
    __syncthreads();

    // ---- out-projection (transposed): C2^T = Wo @ O^T ----------------------
    f32x4 acc2[2][4];
    #pragma unroll
    for (int mt = 0; mt < 2; ++mt)
        #pragma unroll
        for (int n = 0; n < 4; ++n) acc2[mt][n] = vzero;

    #pragma unroll
    for (int ks = 0; ks < 4; ++ks) {
        bf16x8 af2[2];
        #pragma unroll
        for (int mt = 0; mt < 2; ++mt) {
            int wrow = w * 32 + mt * 16 + l;
            if constexpr (USEWS) {
                af2[mt] = *(const bf16x8*)(wbf + 3 * 16384 + wrow * CDIM + ks * 32 + q * 8);
            } else {
                const float* wp = Wo + wrow * CDIM + ks * 32 + q * 8;
                af2[mt] = pack8(((const float4*)wp)[0], ((const float4*)wp)[1]);
            }
        }
        bf16x8 of[4];
        #pragma unroll
        for (int n = 0; n < 4; ++n) {
            const int c8 = ks * 4 + q;
            of[n] = *(const bf16x8*)(sO + (n * 16 + l) * CDIM + ((c8 ^ key) << 3));
        }
        #pragma unroll
        for (int mt = 0; mt < 2; ++mt)
            #pragma unroll
            for (int n = 0; n < 4; ++n)
                acc2[mt][n] = __builtin_amdgcn_mfma_f32_16x16x32_bf16(
                    af2[mt], of[n], acc2[mt][n], 0, 0, 0);
    }
    // epilogue: out[atom][ch] = acc2 + bo, * residue_mask; float4 stores
    #pragma unroll
    for (int n = 0; n < 4; ++n) {
        const long row = m0 + n * 16 + l;
        #pragma unroll
        for (int mt = 0; mt < 2; ++mt) {
            float4 v;
            v.x = (acc2[mt][n][0] + bov[mt][0]) * rm[n];
            v.y = (acc2[mt][n][1] + bov[mt][1]) * rm[n];
            v.z = (acc2[mt][n][2] + bov[mt][2]) * rm[n];
            v.w = (acc2[mt][n][3] + bov[mt][3]) * rm[n];
            *(float4*)(out + row * CDIM + w * 32 + mt * 16 + q * 4) = v;
        }
    }
}

// ------------------------------- launcher -----------------------------------
extern "C" void kernel_launch(void* const* d_in, const int* in_sizes, int n_in,
                              void* d_out, int out_size, void* d_ws, size_t ws_size,
                              hipStream_t stream) {
    const float* x    = (const float*)d_in[0];
    const int*   mask = (const int*)d_in[1];
    const float* Wq   = (const float*)d_in[2];
    const float* bq   = (const float*)d_in[3];
    const float* Wk   = (const float*)d_in[4];
    const float* bk   = (const float*)d_in[5];
    const float* Wv   = (const float*)d_in[6];
    const float* bv   = (const float*)d_in[7];
    const float* Wo   = (const float*)d_in[8];
    const float* bo   = (const float*)d_in[9];
    float* out = (float*)d_out;

    const int nblocks = N_RES / RPB;   // 4096
    const bool usews = ws_size >= (size_t)(4 * 16384 * sizeof(uint16_t));
    if (usews) {
        uint16_t* wbf = (uint16_t*)d_ws;
        wconv_kernel<<<64, 256, 0, stream>>>(Wq, Wk, Wv, Wo, wbf);
        laa_main<true><<<nblocks, 256, 0, stream>>>(x, mask, Wq, bq, Wk, bk, Wv, bv,
                                                    Wo, bo, wbf, out);
    } else {
        laa_main<false><<<nblocks, 256, 0, stream>>>(x, mask, Wq, bq, Wk, bk, Wv, bv,
                                                     Wo, bo, nullptr, out);
    }
}